// Round 6
// baseline (206.616 us; speedup 1.0000x reference)
//
#include <hip/hip_runtime.h>
#include <hip/hip_bf16.h>

#define DM    768
#define HEADS 12
#define DK    64
#define SEQ   2048
#define BATCH 4
#define NE    ((size_t)BATCH * SEQ * DM)   // 6,291,456
#define KT    12                           // 768/64 k-tiles per row-block
#define BRICK 8192                         // 128 rows x 64 k shorts per tile

typedef short v4s __attribute__((ext_vector_type(4)));
typedef short v8s __attribute__((ext_vector_type(8)));
typedef float v4f __attribute__((ext_vector_type(4)));

#define LDS_PTR(p) ((__attribute__((address_space(3))) unsigned int*)(p))
#define GLB_PTR(p) ((const __attribute__((address_space(1))) unsigned int*)(p))

__device__ __forceinline__ unsigned short f2bf(float f) {
    union { float f; unsigned u; } v; v.f = f;
    unsigned r = (v.u + 0x7FFFu + ((v.u >> 16) & 1u)) >> 16;
    return (unsigned short)r;
}
// pack two floats -> two truncated bf16 in one dword (lo = a, hi = b)
__device__ __forceinline__ unsigned pk2(float a, float b) {
    union { float f; unsigned u; } x, y; x.f = a; y.f = b;
    return (x.u >> 16) | (y.u & 0xFFFF0000u);
}
__device__ __forceinline__ unsigned pk2r(float a, float b) {
    return (unsigned)f2bf(a) | ((unsigned)f2bf(b) << 16);
}
__device__ __forceinline__ float fexp2(float x) {
#if __has_builtin(__builtin_amdgcn_exp2f)
    return __builtin_amdgcn_exp2f(x);
#else
    return __expf(x * 0.69314718056f);
#endif
}
// 16x16x16 bf16 MFMA (A 2 VGPR, B 2 VGPR, C/D 4) — name cascade for gfx950
__device__ __forceinline__ v4f mfma16(v4s a, v4s b, v4f c) {
#if __has_builtin(__builtin_amdgcn_mfma_f32_16x16x16_bf16)
    return __builtin_amdgcn_mfma_f32_16x16x16_bf16(a, b, c, 0, 0, 0);
#elif __has_builtin(__builtin_amdgcn_mfma_f32_16x16x16bf16_1k)
    return __builtin_amdgcn_mfma_f32_16x16x16bf16_1k(a, b, c, 0, 0, 0);
#else
    v4f d;
    asm("v_mfma_f32_16x16x16_bf16 %0, %1, %2, %3" : "=&v"(d) : "v"(a), "v"(b), "v"(c));
    return d;
#endif
}

#define QSCALE 0.18033688011112042f   // 0.125 / ln2  (folded into Wq, bq)

// ---------------------------------------------------------------------------
// x fp32 -> bf16, written TILED: [(m>>7)*12 + (k>>6)][m&127][k&63]
// ---------------------------------------------------------------------------
__global__ __launch_bounds__(256)
void cvt_x_kernel(const float* __restrict__ x, unsigned short* __restrict__ xb) {
    const size_t p = ((size_t)blockIdx.x * 256 + threadIdx.x) * 8;
    const int m = (int)(p / DM);
    const int k = (int)(p % DM);
    const float4 a = *(const float4*)(x + p);
    const float4 b = *(const float4*)(x + p + 4);
    v8s o;
    o[0] = (short)f2bf(a.x); o[1] = (short)f2bf(a.y);
    o[2] = (short)f2bf(a.z); o[3] = (short)f2bf(a.w);
    o[4] = (short)f2bf(b.x); o[5] = (short)f2bf(b.y);
    o[6] = (short)f2bf(b.z); o[7] = (short)f2bf(b.w);
    const size_t dst = ((size_t)(m >> 7) * KT + (k >> 6)) * BRICK + (size_t)(m & 127) * 64 + (k & 63);
    *(v8s*)(xb + dst) = o;
}

// ---------------------------------------------------------------------------
// W[k][n] fp32 -> WT tiled: [(n>>7)*12 + (k>>6)][n&127][k&63] bf16.
// z==0 (Wq) scaled by 0.125/ln2 (exp2 path).
// ---------------------------------------------------------------------------
__global__ __launch_bounds__(256)
void cvt_w_kernel(const float* __restrict__ W0, const float* __restrict__ W1,
                  const float* __restrict__ W2, const float* __restrict__ W3,
                  unsigned short* __restrict__ wt) {
    __shared__ unsigned short T[64][72];
    const int z = blockIdx.z;
    const float* W = (z == 0) ? W0 : (z == 1) ? W1 : (z == 2) ? W2 : W3;
    const float scale = (z == 0) ? QSCALE : 1.0f;
    const int k0 = blockIdx.x * 64, n0 = blockIdx.y * 64;
    const int t = threadIdx.x;
    {
        const int kr = t >> 2;
        const int ns = (t & 3) * 16;
        #pragma unroll
        for (int j = 0; j < 4; ++j) {
            const float4 v = *(const float4*)(W + (size_t)(k0 + kr) * DM + n0 + ns + j * 4);
            T[ns + j * 4 + 0][kr] = f2bf(v.x * scale);
            T[ns + j * 4 + 1][kr] = f2bf(v.y * scale);
            T[ns + j * 4 + 2][kr] = f2bf(v.z * scale);
            T[ns + j * 4 + 3][kr] = f2bf(v.w * scale);
        }
    }
    __syncthreads();
    {
        unsigned short* dst = wt + (size_t)z * DM * DM +
            ((size_t)(n0 >> 7) * KT + (k0 >> 6)) * BRICK + (size_t)(n0 & 64) * 64;
        const int n = t >> 2;
        const int ks = (t & 3) * 16;
        #pragma unroll
        for (int j = 0; j < 2; ++j)
            *(v8s*)(dst + (size_t)n * 64 + ks + j * 8) = *(const v8s*)&T[n][ks + j * 8];
    }
}

// ---------------------------------------------------------------------------
// Fused QKV GEMM, single-barrier double-buffered K-loop + XCD swizzle.
// grid 1152 1-D: xcd=idx&7, g=idx>>3; M-block = xcd+8*(g&7), yb = g>>3 (0..17).
// Same-M blocks (sharing A bricks) pin to one XCD -> A stays in XCD L2.
// 128x128 tile, BK=64, global_load_lds 16B, XOR-swizzled LDS, dbuf 64 KB.
// z=0 -> Q[bh][s][d] (pre-scaled), z=1 -> K[bh][s][d], z=2 -> VT[bh][d][s].
// ---------------------------------------------------------------------------
__global__ __launch_bounds__(256)
void gemm_qkv_kernel(const unsigned short* __restrict__ xb, const unsigned short* __restrict__ wtbuf,
                     const float* __restrict__ bq, const float* __restrict__ bk,
                     const float* __restrict__ bv,
                     unsigned short* __restrict__ qb, unsigned short* __restrict__ kb,
                     unsigned short* __restrict__ vtb) {
    __shared__ unsigned short smem[32768];        // As[2] 2x8192 | Bs[2] 2x8192
    const int idx = blockIdx.x;
    const int xcd = idx & 7, g = idx >> 3;
    const int mb = xcd + 8 * (g & 7);             // 0..63
    const int yb = g >> 3;                        // 0..17
    const int z = yb / 6;
    const int N0 = (yb % 6) * 128;
    const float* bias = (z == 0) ? bq : (z == 1) ? bk : bv;
    const float bscale = (z == 0) ? QSCALE : 1.0f;

    const int t = threadIdx.x;
    const int w = t >> 6, lane = t & 63, quad = lane >> 4, l15 = lane & 15;
    const int wm = w >> 1, wn = w & 1;
    const int M0 = mb * 128;

    const unsigned short* gA = xb + (size_t)mb * (KT * BRICK);
    const unsigned short* gB = wtbuf + (size_t)yb * (KT * BRICK);

    const int r8 = lane >> 3;
    const int c8 = (lane & 7) ^ r8;
    const int goff = r8 * 64 + c8 * 8;
    const int rl = l15 & 7, rh = l15 >> 3;

    v4f acc[4][4];
    #pragma unroll
    for (int i = 0; i < 4; ++i)
        #pragma unroll
        for (int j = 0; j < 4; ++j) acc[i][j] = (v4f){0, 0, 0, 0};

    // preload tile 0 into buffer 0
    #pragma unroll
    for (int u = 0; u < 4; ++u) {
        const int win = w * 4 + u;
        __builtin_amdgcn_global_load_lds(GLB_PTR(gA + win * 512 + goff), LDS_PTR(smem + win * 512), 16, 0, 0);
        __builtin_amdgcn_global_load_lds(GLB_PTR(gB + win * 512 + goff), LDS_PTR(smem + 16384 + win * 512), 16, 0, 0);
    }
    __syncthreads();

    for (int kt = 0; kt < KT; ++kt) {
        const int cur = kt & 1;
        // issue async loads for tile kt+1 into the other buffer (overlap compute)
        if (kt + 1 < KT) {
            const unsigned short* ta = gA + (kt + 1) * BRICK;
            const unsigned short* tb = gB + (kt + 1) * BRICK;
            const int nb = (1 - cur) * 8192;
            #pragma unroll
            for (int u = 0; u < 4; ++u) {
                const int win = w * 4 + u;
                __builtin_amdgcn_global_load_lds(GLB_PTR(ta + win * 512 + goff), LDS_PTR(smem + nb + win * 512), 16, 0, 0);
                __builtin_amdgcn_global_load_lds(GLB_PTR(tb + win * 512 + goff), LDS_PTR(smem + 16384 + nb + win * 512), 16, 0, 0);
            }
        }
        const unsigned short* As = smem + cur * 8192;
        const unsigned short* Bs = smem + 16384 + cur * 8192;
        #pragma unroll
        for (int kc = 0; kc < 2; ++kc) {
            const int cs = ((kc << 2) | quad) ^ rl;
            v8s a[4], b[4];
            #pragma unroll
            for (int i = 0; i < 4; ++i)
                a[i] = *(const v8s*)&As[(wm * 8 + i * 2 + rh) * 512 + rl * 64 + cs * 8];
            #pragma unroll
            for (int j = 0; j < 4; ++j)
                b[j] = *(const v8s*)&Bs[(wn * 8 + j * 2 + rh) * 512 + rl * 64 + cs * 8];
            #pragma unroll
            for (int i = 0; i < 4; ++i)
                #pragma unroll
                for (int j = 0; j < 4; ++j)
                    acc[i][j] = __builtin_amdgcn_mfma_f32_16x16x32_bf16(a[i], b[j], acc[i][j], 0, 0, 0);
        }
        __syncthreads();   // drains vmcnt (next-tile loads) + lgkm (this-tile ds reads)
    }

    const int b_ = M0 >> 11;
    const int sidx0 = M0 & 2047;
    const int h0 = N0 >> 6;

    if (z < 2) {   // Q/K: [bh][s][64]
        unsigned short* outp = (z == 0) ? qb : kb;
        #pragma unroll
        for (int j = 0; j < 4; ++j) {
            const int n = N0 + wn * 64 + j * 16 + l15;
            const int h = n >> 6, d = n & 63;
            const float bv_ = bias[n] * bscale;
            #pragma unroll
            for (int i = 0; i < 4; ++i)
                #pragma unroll
                for (int r = 0; r < 4; ++r) {
                    const int sidx = sidx0 + wm * 64 + i * 16 + quad * 4 + r;
                    outp[(((size_t)(b_ * HEADS + h) * SEQ + sidx) << 6) + d] = f2bf(acc[i][j][r] + bv_);
                }
        }
    } else {       // V -> VT[bh][d][s], two m-half phases through LDS
        unsigned short* Ts = smem;                 // [128 dloc][72]
        #pragma unroll
        for (int p = 0; p < 2; ++p) {
            __syncthreads();
            if (wm == p) {
                #pragma unroll
                for (int j = 0; j < 4; ++j) {
                    const int dloc = wn * 64 + j * 16 + l15;
                    const float bv_ = bias[N0 + dloc];
                    #pragma unroll
                    for (int i = 0; i < 4; ++i)
                        #pragma unroll
                        for (int r = 0; r < 4; ++r)
                            Ts[dloc * 72 + i * 16 + quad * 4 + r] = f2bf(acc[i][j][r] + bv_);
                }
            }
            __syncthreads();
            const int dloc = t >> 1, ms = (t & 1) * 32;
            const int h = h0 + (dloc >> 6), d = dloc & 63;
            unsigned short* dst = vtb + (((size_t)(b_ * HEADS + h) * DK + d) << 11) + sidx0 + p * 64 + ms;
            #pragma unroll
            for (int jj = 0; jj < 4; ++jj)
                *(v8s*)(dst + jj * 8) = *(const v8s*)&Ts[dloc * 72 + ms + jj * 8];
        }
    }
}

// ---------------------------------------------------------------------------
// Output projection: 128x128 tiles, dbuf single-barrier K-loop + XCD swizzle.
// grid 384 1-D: xcd=idx&7, g=idx>>3; M-block = xcd+8*(g&7), nb = g>>3 (0..5).
// out fp32 [8192][768] = ob(tiled bf16) @ WoT + bo
// ---------------------------------------------------------------------------
__global__ __launch_bounds__(256)
void gemm_out_kernel(const unsigned short* __restrict__ ob, const unsigned short* __restrict__ wto,
                     const float* __restrict__ bias, float* __restrict__ out) {
    __shared__ unsigned short smem[32768];
    const int idx = blockIdx.x;
    const int xcd = idx & 7, g = idx >> 3;
    const int mb = xcd + 8 * (g & 7);             // 0..63
    const int nb = g >> 3;                        // 0..5
    const int t = threadIdx.x;
    const int w = t >> 6, lane = t & 63, quad = lane >> 4, l15 = lane & 15;
    const int wm = w >> 1, wn = w & 1;
    const int M0 = mb * 128;
    const int N0 = nb * 128;

    const unsigned short* gA = ob + (size_t)mb * (KT * BRICK);
    const unsigned short* gB = wto + (size_t)nb * (KT * BRICK);

    const int r8 = lane >> 3;
    const int c8 = (lane & 7) ^ r8;
    const int goff = r8 * 64 + c8 * 8;
    const int rl = l15 & 7, rh = l15 >> 3;

    v4f acc[4][4];
    #pragma unroll
    for (int i = 0; i < 4; ++i)
        #pragma unroll
        for (int j = 0; j < 4; ++j) acc[i][j] = (v4f){0, 0, 0, 0};

    #pragma unroll
    for (int u = 0; u < 4; ++u) {
        const int win = w * 4 + u;
        __builtin_amdgcn_global_load_lds(GLB_PTR(gA + win * 512 + goff), LDS_PTR(smem + win * 512), 16, 0, 0);
        __builtin_amdgcn_global_load_lds(GLB_PTR(gB + win * 512 + goff), LDS_PTR(smem + 16384 + win * 512), 16, 0, 0);
    }
    __syncthreads();

    for (int kt = 0; kt < KT; ++kt) {
        const int cur = kt & 1;
        if (kt + 1 < KT) {
            const unsigned short* ta = gA + (kt + 1) * BRICK;
            const unsigned short* tb = gB + (kt + 1) * BRICK;
            const int nxt = (1 - cur) * 8192;
            #pragma unroll
            for (int u = 0; u < 4; ++u) {
                const int win = w * 4 + u;
                __builtin_amdgcn_global_load_lds(GLB_PTR(ta + win * 512 + goff), LDS_PTR(smem + nxt + win * 512), 16, 0, 0);
                __builtin_amdgcn_global_load_lds(GLB_PTR(tb + win * 512 + goff), LDS_PTR(smem + 16384 + nxt + win * 512), 16, 0, 0);
            }
        }
        const unsigned short* As = smem + cur * 8192;
        const unsigned short* Bs = smem + 16384 + cur * 8192;
        #pragma unroll
        for (int kc = 0; kc < 2; ++kc) {
            const int cs = ((kc << 2) | quad) ^ rl;
            v8s a[4], b[4];
            #pragma unroll
            for (int i = 0; i < 4; ++i)
                a[i] = *(const v8s*)&As[(wm * 8 + i * 2 + rh) * 512 + rl * 64 + cs * 8];
            #pragma unroll
            for (int j = 0; j < 4; ++j)
                b[j] = *(const v8s*)&Bs[(wn * 8 + j * 2 + rh) * 512 + rl * 64 + cs * 8];
            #pragma unroll
            for (int i = 0; i < 4; ++i)
                #pragma unroll
                for (int j = 0; j < 4; ++j)
                    acc[i][j] = __builtin_amdgcn_mfma_f32_16x16x32_bf16(a[i], b[j], acc[i][j], 0, 0, 0);
        }
        __syncthreads();
    }

    #pragma unroll
    for (int j = 0; j < 4; ++j) {
        const int n = N0 + wn * 64 + j * 16 + l15;
        const float bv_ = bias[n];
        #pragma unroll
        for (int i = 0; i < 4; ++i)
            #pragma unroll
            for (int r = 0; r < 4; ++r) {
                const int m = M0 + wm * 64 + i * 16 + quad * 4 + r;
                out[(size_t)m * DM + n] = acc[i][j][r] + bv_;
            }
    }
}

// ---------------------------------------------------------------------------
// Causal flash attention. QK^T as S^T = mfma_16x16x32(K, Q); PV now as
// O[q][d] = sum_s4 mfma_16x16x16(P-frag, V-frag): the S^T output fragment
// p[s4][r] IS the 16x16x16 A-operand (m=q=l15, k=4quad+r, chunk=s4), so P
// packs straight from registers -> NO Ps LDS round-trip. V B-fragment reads
// as ds_read_b64 from the same swizzled Vb[d][key] layout. LDS = K/V dbuf
// in exactly 32 KB -> 5 blocks/CU AND single barrier per tile (R3 structure
// + R5 occupancy). 1536 blocks (48 bh x 32 strips), longest-first, backfill.
// Row-sum via ones-MFMA (os[r], q=4quad+r); causal mask diag-only; exp2.
// ---------------------------------------------------------------------------
__global__ __launch_bounds__(256, 5)
void attn_kernel(const unsigned short* __restrict__ Q, const unsigned short* __restrict__ K,
                 const unsigned short* __restrict__ VT, unsigned short* __restrict__ O) {
    __shared__ unsigned short smem[16384];     // 32 KB: Kb[2] 2x8K | Vb[2] 2x8K
    const int t = threadIdx.x;
    const int w = t >> 6, lane = t & 63, quad = lane >> 4, l15 = lane & 15;
    const int e7 = l15 & 7;
    const int q1 = quad >> 1, q0x = quad & 1;

    const int idx = blockIdx.x;
    const int xcd = idx & 7;
    const int g   = idx >> 3;                  // 0..191
    const int bh  = xcd + 8 * (g % 6);         // 0..47 (same-bh -> same XCD, L2 reuse)
    const int s   = 31 - g / 6;                // longest strips dispatched first
    const int q0  = s * 64;
    const int nkt = s + 1;
    const size_t kvbase = (size_t)bh * SEQ * DK;

    v8s qf[2];
    #pragma unroll
    for (int c = 0; c < 2; ++c)
        qf[c] = *(const v8s*)(Q + kvbase + (size_t)(q0 + w * 16 + l15) * DK + c * 32 + quad * 8);

    v4f o[4];                                  // O[q=4quad+r][d = nf*16 + l15]
    #pragma unroll
    for (int nf = 0; nf < 4; ++nf) o[nf] = (v4f){0, 0, 0, 0};
    v4f os = (v4f){0, 0, 0, 0};                // row-sums: os[r] for q=4quad+r
    const v4f zero4 = (v4f){0, 0, 0, 0};       // persistent C=0 operand

    const short one_bf = (short)0x3F80;        // bf16 1.0
    const v4s ones4 = (v4s){one_bf, one_bf, one_bf, one_bf};

    const int srow = t >> 3;                   // 0..31
    const int sc16 = t & 7;                    // 16B-slot within row
    const int scolsw = (sc16 ^ (srow & 7)) * 8;// swizzled short offset ((srow+32)&7 == srow&7)
    const int gcol = sc16 * 8;                 // global short offset
    const int so0 = srow * 64 + scolsw;        // LDS short offset, row srow
    const int so1 = (srow + 32) * 64 + scolsw; // LDS short offset, row srow+32

    v8s kr0 = *(const v8s*)(K  + kvbase + (size_t)srow * DK + gcol);
    v8s kr1 = *(const v8s*)(K  + kvbase + (size_t)(srow + 32) * DK + gcol);
    v8s vr0 = *(const v8s*)(VT + kvbase + ((size_t)srow << 11) + gcol);
    v8s vr1 = *(const v8s*)(VT + kvbase + ((size_t)(srow + 32) << 11) + gcol);
    *(v8s*)&smem[so0]        = kr0;            // Kb[0]
    *(v8s*)&smem[so1]        = kr1;
    *(v8s*)&smem[8192 + so0] = vr0;            // Vb[0]
    *(v8s*)&smem[8192 + so1] = vr1;
    __syncthreads();

    const int q_ = q0 + w * 16 + l15;

    int cur = 0;
    for (int kt = 0; kt < nkt; ++kt) {
        const int k0 = kt * 64;
        if (kt + 1 < nkt) {                    // prefetch next tile into registers
            const int kn = k0 + 64;
            kr0 = *(const v8s*)(K  + kvbase + (size_t)(kn + srow) * DK + gcol);
            kr1 = *(const v8s*)(K  + kvbase + (size_t)(kn + srow + 32) * DK + gcol);
            vr0 = *(const v8s*)(VT + kvbase + ((size_t)srow << 11) + kn + gcol);
            vr1 = *(const v8s*)(VT + kvbase + ((size_t)(srow + 32) << 11) + kn + gcol);
        }
        const unsigned short* Kc = smem + cur * 4096;
        const unsigned short* Vc = smem + 8192 + cur * 4096;

        // QK^T: sc[s4][r] = S^T[key = k0+16*s4+4*quad+r][q = l15]
        v4f sc[4];
        #pragma unroll
        for (int s4 = 0; s4 < 4; ++s4) {
            const v8s kf = *(const v8s*)&Kc[(s4 * 16 + l15) * 64 + ((quad ^ e7) << 3)];
            sc[s4] = __builtin_amdgcn_mfma_f32_16x16x32_bf16(kf, qf[0], zero4, 0, 0, 0);
        }
        #pragma unroll
        for (int s4 = 0; s4 < 4; ++s4) {
            const v8s kf = *(const v8s*)&Kc[(s4 * 16 + l15) * 64 + (((4 | quad) ^ e7) << 3)];
            sc[s4] = __builtin_amdgcn_mfma_f32_16x16x32_bf16(kf, qf[1], sc[s4], 0, 0, 0);
        }

        // softmax numerator -> packed bf16 A-fragments (registers only)
        v4s pa[4];
        {
            const bool msk = (kt == s);
            #pragma unroll
            for (int s4 = 0; s4 < 4; ++s4) {
                float p[4];
                #pragma unroll
                for (int r = 0; r < 4; ++r) p[r] = fexp2(sc[s4][r]);
                if (msk) {   // diagonal tile only: uniform branch, per-lane mask
                    #pragma unroll
                    for (int r = 0; r < 4; ++r) {
                        const int key = k0 + s4 * 16 + quad * 4 + r;
                        if (key > q_) p[r] = 0.f;
                    }
                }
                union { unsigned u[2]; v4s s; } pu;
                pu.u[0] = pk2(p[0], p[1]); pu.u[1] = pk2(p[2], p[3]);
                pa[s4] = pu.s;
            }
        }

        // PV: O[q][d] += P V  via 16x16x16 (B = V[key 4-chunk][d=l15], b64 reads)
        #pragma unroll
        for (int nf = 0; nf < 4; ++nf) {
            const int rowb = (nf * 16 + l15) * 64;
            #pragma unroll
            for (int s4 = 0; s4 < 4; ++s4) {
                const v4s vb = *(const v4s*)&Vc[rowb + (((2 * s4 + q1) ^ e7) << 3) + (q0x << 2)];
                o[nf] = mfma16(pa[s4], vb, o[nf]);
            }
        }
        #pragma unroll
        for (int s4 = 0; s4 < 4; ++s4)
            os = mfma16(pa[s4], ones4, os);

        if (kt + 1 < nkt) {                    // publish prefetched tile into other buffer
            const int nb = (cur ^ 1) * 4096;
            *(v8s*)&smem[nb + so0]        = kr0;
            *(v8s*)&smem[nb + so1]        = kr1;
            *(v8s*)&smem[8192 + nb + so0] = vr0;
            *(v8s*)&smem[8192 + nb + so1] = vr1;
        }
        __syncthreads();                       // single barrier per tile (dbuf)
        cur ^= 1;
    }

    // normalize: os[r] = row-sum for q=4quad+r; o[nf][r] shares that q
    float inv[4];
    #pragma unroll
    for (int r = 0; r < 4; ++r) inv[r] = 1.f / os[r];

    const int b = bh / HEADS, h = bh % HEADS;
    const size_t br = ((size_t)(b * 16 + (q0 >> 7)) * KT + h) * BRICK;
    const int rowb = (q0 & 127) + w * 16 + quad * 4;
    #pragma unroll
    for (int nf = 0; nf < 4; ++nf)
        #pragma unroll
        for (int r = 0; r < 4; ++r)
            O[br + (size_t)(rowb + r) * 64 + nf * 16 + l15] = f2bf(o[nf][r] * inv[r]);
}

extern "C" void kernel_launch(void* const* d_in, const int* in_sizes, int n_in,
                              void* d_out, int out_size, void* d_ws, size_t ws_size,
                              hipStream_t stream) {
    const float* x  = (const float*)d_in[0];
    const float* Wq = (const float*)d_in[1];
    const float* bq = (const float*)d_in[2];
    const float* Wk = (const float*)d_in[3];
    const float* bk = (const float*)d_in[4];
    const float* Wv = (const float*)d_in[5];
    const float* bv = (const float*)d_in[6];
    const float* Wo = (const float*)d_in[7];
    const float* bo = (const float*)d_in[8];
    float* out = (float*)d_out;

    unsigned short* xb  = (unsigned short*)d_ws;      // tiled [8192][768] bf16; reused as ob
    unsigned short* qb  = xb  + NE;                   // [bh][s][64]
    unsigned short* kb  = qb  + NE;                   // [bh][s][64]
    unsigned short* vtb = kb  + NE;                   // [bh][64][s]
    unsigned short* wt  = vtb + NE;                   // 4 x [768][768] bf16 tiled (q,k,v,o)
    unsigned short* ob  = xb;                         // alias (xb dead after gemm_qkv)

    cvt_x_kernel<<<dim3(NE / (8 * 256)), 256, 0, stream>>>(x, xb);
    cvt_w_kernel<<<dim3(12, 12, 4), 256, 0, stream>>>(Wq, Wk, Wv, Wo, wt);
    gemm_qkv_kernel<<<dim3(1152), 256, 0, stream>>>(xb, wt, bq, bk, bv, qb, kb, vtb);
    attn_kernel<<<dim3(1536), 256, 0, stream>>>(qb, kb, vtb, ob);
    gemm_out_kernel<<<dim3(384), 256, 0, stream>>>(ob, wt + (size_t)3 * DM * DM, bo, out);
}

// Round 7
// 189.531 us; speedup vs baseline: 1.0901x; 1.0901x over previous
//
#include <hip/hip_runtime.h>
#include <hip/hip_bf16.h>

#define DM    768
#define HEADS 12
#define DK    64
#define SEQ   2048
#define BATCH 4
#define NE    ((size_t)BATCH * SEQ * DM)   // 6,291,456
#define KT    12                           // 768/64 k-tiles per row-block
#define BRICK 8192                         // 128 rows x 64 k shorts per tile

typedef short v8s __attribute__((ext_vector_type(8)));
typedef float v4f __attribute__((ext_vector_type(4)));

#define LDS_PTR(p) ((__attribute__((address_space(3))) unsigned int*)(p))
#define GLB_PTR(p) ((const __attribute__((address_space(1))) unsigned int*)(p))

__device__ __forceinline__ unsigned short f2bf(float f) {
    union { float f; unsigned u; } v; v.f = f;
    unsigned r = (v.u + 0x7FFFu + ((v.u >> 16) & 1u)) >> 16;
    return (unsigned short)r;
}
// pack two floats -> two truncated bf16 in one dword (lo = a, hi = b)
__device__ __forceinline__ unsigned pk2(float a, float b) {
    union { float f; unsigned u; } x, y; x.f = a; y.f = b;
    return (x.u >> 16) | (y.u & 0xFFFF0000u);
}
__device__ __forceinline__ unsigned pk2r(float a, float b) {
    return (unsigned)f2bf(a) | ((unsigned)f2bf(b) << 16);
}
__device__ __forceinline__ float fexp2(float x) {
#if __has_builtin(__builtin_amdgcn_exp2f)
    return __builtin_amdgcn_exp2f(x);
#else
    return __expf(x * 0.69314718056f);
#endif
}

#define QSCALE 0.18033688011112042f   // 0.125 / ln2  (folded into Wq, bq)

// ---------------------------------------------------------------------------
// x fp32 -> bf16, written TILED: [(m>>7)*12 + (k>>6)][m&127][k&63]
// ---------------------------------------------------------------------------
__global__ __launch_bounds__(256)
void cvt_x_kernel(const float* __restrict__ x, unsigned short* __restrict__ xb) {
    const size_t p = ((size_t)blockIdx.x * 256 + threadIdx.x) * 8;
    const int m = (int)(p / DM);
    const int k = (int)(p % DM);
    const float4 a = *(const float4*)(x + p);
    const float4 b = *(const float4*)(x + p + 4);
    v8s o;
    o[0] = (short)f2bf(a.x); o[1] = (short)f2bf(a.y);
    o[2] = (short)f2bf(a.z); o[3] = (short)f2bf(a.w);
    o[4] = (short)f2bf(b.x); o[5] = (short)f2bf(b.y);
    o[6] = (short)f2bf(b.z); o[7] = (short)f2bf(b.w);
    const size_t dst = ((size_t)(m >> 7) * KT + (k >> 6)) * BRICK + (size_t)(m & 127) * 64 + (k & 63);
    *(v8s*)(xb + dst) = o;
}

// ---------------------------------------------------------------------------
// W[k][n] fp32 -> WT tiled: [(n>>7)*12 + (k>>6)][n&127][k&63] bf16.
// z==0 (Wq) scaled by 0.125/ln2 (exp2 path).
// ---------------------------------------------------------------------------
__global__ __launch_bounds__(256)
void cvt_w_kernel(const float* __restrict__ W0, const float* __restrict__ W1,
                  const float* __restrict__ W2, const float* __restrict__ W3,
                  unsigned short* __restrict__ wt) {
    __shared__ unsigned short T[64][72];
    const int z = blockIdx.z;
    const float* W = (z == 0) ? W0 : (z == 1) ? W1 : (z == 2) ? W2 : W3;
    const float scale = (z == 0) ? QSCALE : 1.0f;
    const int k0 = blockIdx.x * 64, n0 = blockIdx.y * 64;
    const int t = threadIdx.x;
    {
        const int kr = t >> 2;
        const int ns = (t & 3) * 16;
        #pragma unroll
        for (int j = 0; j < 4; ++j) {
            const float4 v = *(const float4*)(W + (size_t)(k0 + kr) * DM + n0 + ns + j * 4);
            T[ns + j * 4 + 0][kr] = f2bf(v.x * scale);
            T[ns + j * 4 + 1][kr] = f2bf(v.y * scale);
            T[ns + j * 4 + 2][kr] = f2bf(v.z * scale);
            T[ns + j * 4 + 3][kr] = f2bf(v.w * scale);
        }
    }
    __syncthreads();
    {
        unsigned short* dst = wt + (size_t)z * DM * DM +
            ((size_t)(n0 >> 7) * KT + (k0 >> 6)) * BRICK + (size_t)(n0 & 64) * 64;
        const int n = t >> 2;
        const int ks = (t & 3) * 16;
        #pragma unroll
        for (int j = 0; j < 2; ++j)
            *(v8s*)(dst + (size_t)n * 64 + ks + j * 8) = *(const v8s*)&T[n][ks + j * 8];
    }
}

// ---------------------------------------------------------------------------
// Fused QKV GEMM, single-barrier double-buffered K-loop + XCD swizzle.
// grid 1152 1-D: xcd=idx&7, g=idx>>3; M-block = xcd+8*(g&7), yb = g>>3 (0..17).
// Same-M blocks (sharing A bricks) pin to one XCD -> A stays in XCD L2.
// 128x128 tile, BK=64, global_load_lds 16B, XOR-swizzled LDS, dbuf 64 KB.
// z=0 -> Q[bh][s][d] (pre-scaled), z=1 -> K[bh][s][d], z=2 -> VT[bh][d][s].
// ---------------------------------------------------------------------------
__global__ __launch_bounds__(256)
void gemm_qkv_kernel(const unsigned short* __restrict__ xb, const unsigned short* __restrict__ wtbuf,
                     const float* __restrict__ bq, const float* __restrict__ bk,
                     const float* __restrict__ bv,
                     unsigned short* __restrict__ qb, unsigned short* __restrict__ kb,
                     unsigned short* __restrict__ vtb) {
    __shared__ unsigned short smem[32768];        // As[2] 2x8192 | Bs[2] 2x8192
    const int idx = blockIdx.x;
    const int xcd = idx & 7, g = idx >> 3;
    const int mb = xcd + 8 * (g & 7);             // 0..63
    const int yb = g >> 3;                        // 0..17
    const int z = yb / 6;
    const int N0 = (yb % 6) * 128;
    const float* bias = (z == 0) ? bq : (z == 1) ? bk : bv;
    const float bscale = (z == 0) ? QSCALE : 1.0f;

    const int t = threadIdx.x;
    const int w = t >> 6, lane = t & 63, quad = lane >> 4, l15 = lane & 15;
    const int wm = w >> 1, wn = w & 1;
    const int M0 = mb * 128;

    const unsigned short* gA = xb + (size_t)mb * (KT * BRICK);
    const unsigned short* gB = wtbuf + (size_t)yb * (KT * BRICK);

    const int r8 = lane >> 3;
    const int c8 = (lane & 7) ^ r8;
    const int goff = r8 * 64 + c8 * 8;
    const int rl = l15 & 7, rh = l15 >> 3;

    v4f acc[4][4];
    #pragma unroll
    for (int i = 0; i < 4; ++i)
        #pragma unroll
        for (int j = 0; j < 4; ++j) acc[i][j] = (v4f){0, 0, 0, 0};

    // preload tile 0 into buffer 0
    #pragma unroll
    for (int u = 0; u < 4; ++u) {
        const int win = w * 4 + u;
        __builtin_amdgcn_global_load_lds(GLB_PTR(gA + win * 512 + goff), LDS_PTR(smem + win * 512), 16, 0, 0);
        __builtin_amdgcn_global_load_lds(GLB_PTR(gB + win * 512 + goff), LDS_PTR(smem + 16384 + win * 512), 16, 0, 0);
    }
    __syncthreads();

    for (int kt = 0; kt < KT; ++kt) {
        const int cur = kt & 1;
        // issue async loads for tile kt+1 into the other buffer (overlap compute)
        if (kt + 1 < KT) {
            const unsigned short* ta = gA + (kt + 1) * BRICK;
            const unsigned short* tb = gB + (kt + 1) * BRICK;
            const int nb = (1 - cur) * 8192;
            #pragma unroll
            for (int u = 0; u < 4; ++u) {
                const int win = w * 4 + u;
                __builtin_amdgcn_global_load_lds(GLB_PTR(ta + win * 512 + goff), LDS_PTR(smem + nb + win * 512), 16, 0, 0);
                __builtin_amdgcn_global_load_lds(GLB_PTR(tb + win * 512 + goff), LDS_PTR(smem + 16384 + nb + win * 512), 16, 0, 0);
            }
        }
        const unsigned short* As = smem + cur * 8192;
        const unsigned short* Bs = smem + 16384 + cur * 8192;
        #pragma unroll
        for (int kc = 0; kc < 2; ++kc) {
            const int cs = ((kc << 2) | quad) ^ rl;
            v8s a[4], b[4];
            #pragma unroll
            for (int i = 0; i < 4; ++i)
                a[i] = *(const v8s*)&As[(wm * 8 + i * 2 + rh) * 512 + rl * 64 + cs * 8];
            #pragma unroll
            for (int j = 0; j < 4; ++j)
                b[j] = *(const v8s*)&Bs[(wn * 8 + j * 2 + rh) * 512 + rl * 64 + cs * 8];
            #pragma unroll
            for (int i = 0; i < 4; ++i)
                #pragma unroll
                for (int j = 0; j < 4; ++j)
                    acc[i][j] = __builtin_amdgcn_mfma_f32_16x16x32_bf16(a[i], b[j], acc[i][j], 0, 0, 0);
        }
        __syncthreads();   // drains vmcnt (next-tile loads) + lgkm (this-tile ds reads)
    }

    const int b_ = M0 >> 11;
    const int sidx0 = M0 & 2047;
    const int h0 = N0 >> 6;

    if (z < 2) {   // Q/K: [bh][s][64]
        unsigned short* outp = (z == 0) ? qb : kb;
        #pragma unroll
        for (int j = 0; j < 4; ++j) {
            const int n = N0 + wn * 64 + j * 16 + l15;
            const int h = n >> 6, d = n & 63;
            const float bv_ = bias[n] * bscale;
            #pragma unroll
            for (int i = 0; i < 4; ++i)
                #pragma unroll
                for (int r = 0; r < 4; ++r) {
                    const int sidx = sidx0 + wm * 64 + i * 16 + quad * 4 + r;
                    outp[(((size_t)(b_ * HEADS + h) * SEQ + sidx) << 6) + d] = f2bf(acc[i][j][r] + bv_);
                }
        }
    } else {       // V -> VT[bh][d][s], two m-half phases through LDS
        unsigned short* Ts = smem;                 // [128 dloc][72]
        #pragma unroll
        for (int p = 0; p < 2; ++p) {
            __syncthreads();
            if (wm == p) {
                #pragma unroll
                for (int j = 0; j < 4; ++j) {
                    const int dloc = wn * 64 + j * 16 + l15;
                    const float bv_ = bias[N0 + dloc];
                    #pragma unroll
                    for (int i = 0; i < 4; ++i)
                        #pragma unroll
                        for (int r = 0; r < 4; ++r)
                            Ts[dloc * 72 + i * 16 + quad * 4 + r] = f2bf(acc[i][j][r] + bv_);
                }
            }
            __syncthreads();
            const int dloc = t >> 1, ms = (t & 1) * 32;
            const int h = h0 + (dloc >> 6), d = dloc & 63;
            unsigned short* dst = vtb + (((size_t)(b_ * HEADS + h) * DK + d) << 11) + sidx0 + p * 64 + ms;
            #pragma unroll
            for (int jj = 0; jj < 4; ++jj)
                *(v8s*)(dst + jj * 8) = *(const v8s*)&Ts[dloc * 72 + ms + jj * 8];
        }
    }
}

// ---------------------------------------------------------------------------
// Output projection RETILED 128x64: grid 768 1-D (3 blocks/CU uniform,
// all-resident — fixes the 384-block 1.5/CU residency trap).
// xcd=idx&7, g=idx>>3; mb = xcd+8*(g&7) (0..63), nb = g>>3 (0..11), N0=nb*64.
// As 16KB + Bs 8KB per buffer, dbuf 48KB LDS. acc[4][2], 16 MFMA/wave/k-tile.
// out fp32 [8192][768] = ob(tiled bf16) @ WoT + bo
// ---------------------------------------------------------------------------
__global__ __launch_bounds__(256)
void gemm_out_kernel(const unsigned short* __restrict__ ob, const unsigned short* __restrict__ wto,
                     const float* __restrict__ bias, float* __restrict__ out) {
    __shared__ unsigned short smem[24576];        // As[2] 2x8192 | Bs[2] 2x4096
    const int idx = blockIdx.x;
    const int xcd = idx & 7, g = idx >> 3;
    const int mb = xcd + 8 * (g & 7);             // 0..63
    const int nb = g >> 3;                        // 0..11
    const int t = threadIdx.x;
    const int w = t >> 6, lane = t & 63, quad = lane >> 4, l15 = lane & 15;
    const int wm = w >> 1, wn = w & 1;
    const int M0 = mb * 128;
    const int N0 = nb * 64;

    const unsigned short* gA = ob + (size_t)mb * (KT * BRICK);
    // wto half-brick for this 64-col slab: [(nb>>1)*12 + kt]*8192 + (nb&1)*4096
    const unsigned short* gB = wto + (size_t)(nb >> 1) * (KT * BRICK) + (nb & 1) * 4096;

    const int r8 = lane >> 3;
    const int c8 = (lane & 7) ^ r8;
    const int goff = r8 * 64 + c8 * 8;
    const int rl = l15 & 7, rh = l15 >> 3;

    v4f acc[4][2];
    #pragma unroll
    for (int i = 0; i < 4; ++i)
        #pragma unroll
        for (int j = 0; j < 2; ++j) acc[i][j] = (v4f){0, 0, 0, 0};

    #pragma unroll
    for (int u = 0; u < 4; ++u) {
        const int win = w * 4 + u;
        __builtin_amdgcn_global_load_lds(GLB_PTR(gA + win * 512 + goff), LDS_PTR(smem + win * 512), 16, 0, 0);
    }
    #pragma unroll
    for (int u = 0; u < 2; ++u) {
        const int win = w * 2 + u;
        __builtin_amdgcn_global_load_lds(GLB_PTR(gB + win * 512 + goff), LDS_PTR(smem + 16384 + win * 512), 16, 0, 0);
    }
    __syncthreads();

    for (int kt = 0; kt < KT; ++kt) {
        const int cur = kt & 1;
        if (kt + 1 < KT) {
            const unsigned short* ta = gA + (kt + 1) * BRICK;
            const unsigned short* tb = gB + (kt + 1) * BRICK;
            #pragma unroll
            for (int u = 0; u < 4; ++u) {
                const int win = w * 4 + u;
                __builtin_amdgcn_global_load_lds(GLB_PTR(ta + win * 512 + goff),
                                                 LDS_PTR(smem + (1 - cur) * 8192 + win * 512), 16, 0, 0);
            }
            #pragma unroll
            for (int u = 0; u < 2; ++u) {
                const int win = w * 2 + u;
                __builtin_amdgcn_global_load_lds(GLB_PTR(tb + win * 512 + goff),
                                                 LDS_PTR(smem + 16384 + (1 - cur) * 4096 + win * 512), 16, 0, 0);
            }
        }
        const unsigned short* As = smem + cur * 8192;
        const unsigned short* Bs = smem + 16384 + cur * 4096;
        #pragma unroll
        for (int kc = 0; kc < 2; ++kc) {
            const int cs = ((kc << 2) | quad) ^ rl;
            v8s a[4], b[2];
            #pragma unroll
            for (int i = 0; i < 4; ++i)
                a[i] = *(const v8s*)&As[(wm * 8 + i * 2 + rh) * 512 + rl * 64 + cs * 8];
            #pragma unroll
            for (int j = 0; j < 2; ++j)
                b[j] = *(const v8s*)&Bs[(wn * 4 + j * 2 + rh) * 512 + rl * 64 + cs * 8];
            #pragma unroll
            for (int i = 0; i < 4; ++i)
                #pragma unroll
                for (int j = 0; j < 2; ++j)
                    acc[i][j] = __builtin_amdgcn_mfma_f32_16x16x32_bf16(a[i], b[j], acc[i][j], 0, 0, 0);
        }
        __syncthreads();
    }

    #pragma unroll
    for (int j = 0; j < 2; ++j) {
        const int n = N0 + wn * 32 + j * 16 + l15;
        const float bv_ = bias[n];
        #pragma unroll
        for (int i = 0; i < 4; ++i)
            #pragma unroll
            for (int r = 0; r < 4; ++r) {
                const int m = M0 + wm * 64 + i * 16 + quad * 4 + r;
                out[(size_t)m * DM + n] = acc[i][j][r] + bv_;
            }
    }
}

// ---------------------------------------------------------------------------
// Causal flash attention (R3-proven version, 50.2 us). S^T formulation
// (A=K, B=Q -> C = S^T; PV as O^T = V^T P^T). 1536 blocks (48 bh x 32
// q-tiles), 64-query strip per 256-thread block, longest-first, backfilled.
// LDS 40 KB ([64][64] XOR-swizzled dbuf K/V + Ps) -> 4 blocks/CU, single
// barrier per tile. Row-sum via ones-MFMA; mask diag-only; exp2 path.
// ---------------------------------------------------------------------------
__global__ __launch_bounds__(256, 4)
void attn_kernel(const unsigned short* __restrict__ Q, const unsigned short* __restrict__ K,
                 const unsigned short* __restrict__ VT, unsigned short* __restrict__ O) {
    __shared__ unsigned short Kb[2][64][64];   // [buf][key][dk]   16B-XOR swizzled
    __shared__ unsigned short Vb[2][64][64];   // [buf][dk][key]   16B-XOR swizzled
    __shared__ unsigned short Ps[4][16][64];   // [wave][query][key] swizzled P^T round-trip
    const int t = threadIdx.x;
    const int w = t >> 6, lane = t & 63, quad = lane >> 4, l15 = lane & 15;
    const int e7 = l15 & 7;

    const int idx = blockIdx.x;
    const int xcd = idx & 7;
    const int g   = idx >> 3;                  // 0..191
    const int bh  = xcd + 8 * (g % 6);         // 0..47 (same-bh -> same XCD, L2 reuse)
    const int s   = 31 - g / 6;                // longest strips dispatched first
    const int q0  = s * 64;
    const int nkt = s + 1;
    const size_t kvbase = (size_t)bh * SEQ * DK;

    v8s qf[2];
    #pragma unroll
    for (int c = 0; c < 2; ++c)
        qf[c] = *(const v8s*)(Q + kvbase + (size_t)(q0 + w * 16 + l15) * DK + c * 32 + quad * 8);

    v4f o[4];                                  // O^T: [d-quarter][r]; col=query=l15
    #pragma unroll
    for (int nf = 0; nf < 4; ++nf) o[nf] = (v4f){0, 0, 0, 0};
    v4f os = (v4f){0, 0, 0, 0};                // row-sum accumulator (ones-MFMA)
    const v4f zero4 = (v4f){0, 0, 0, 0};       // persistent C=0 operand

    const short one_bf = (short)0x3F80;        // bf16 1.0
    const v8s ones = (v8s){one_bf, one_bf, one_bf, one_bf, one_bf, one_bf, one_bf, one_bf};

    const int srow = t >> 3;                   // 0..31
    const int sc16 = t & 7;                    // 16B-slot within row
    const int scolsw = (sc16 ^ (srow & 7)) * 8;// swizzled short offset ((srow+32)&7 == srow&7)
    const int gcol = sc16 * 8;                 // global short offset

    v8s kr0 = *(const v8s*)(K  + kvbase + (size_t)srow * DK + gcol);
    v8s kr1 = *(const v8s*)(K  + kvbase + (size_t)(srow + 32) * DK + gcol);
    v8s vr0 = *(const v8s*)(VT + kvbase + ((size_t)srow << 11) + gcol);
    v8s vr1 = *(const v8s*)(VT + kvbase + ((size_t)(srow + 32) << 11) + gcol);
    *(v8s*)&Kb[0][srow][scolsw]      = kr0;
    *(v8s*)&Kb[0][srow + 32][scolsw] = kr1;
    *(v8s*)&Vb[0][srow][scolsw]      = vr0;
    *(v8s*)&Vb[0][srow + 32][scolsw] = vr1;
    __syncthreads();

    const int q_ = q0 + w * 16 + l15;

    for (int kt = 0; kt < nkt; ++kt) {
        const int k0 = kt * 64;
        const int cur = kt & 1;
        if (kt + 1 < nkt) {
            const int kn = k0 + 64;
            kr0 = *(const v8s*)(K  + kvbase + (size_t)(kn + srow) * DK + gcol);
            kr1 = *(const v8s*)(K  + kvbase + (size_t)(kn + srow + 32) * DK + gcol);
            vr0 = *(const v8s*)(VT + kvbase + ((size_t)srow << 11) + kn + gcol);
            vr1 = *(const v8s*)(VT + kvbase + ((size_t)(srow + 32) << 11) + kn + gcol);
        }

        // QK^T: sc[s4][r] = S^T[key = k0+16*s4+4*quad+r][q = l15]
        v4f sc[4];
        #pragma unroll
        for (int s4 = 0; s4 < 4; ++s4) {
            const v8s kf = *(const v8s*)&Kb[cur][s4 * 16 + l15][(quad ^ e7) * 8];
            sc[s4] = __builtin_amdgcn_mfma_f32_16x16x32_bf16(kf, qf[0], zero4, 0, 0, 0);
        }
        #pragma unroll
        for (int s4 = 0; s4 < 4; ++s4) {
            const v8s kf = *(const v8s*)&Kb[cur][s4 * 16 + l15][((4 | quad) ^ e7) * 8];
            sc[s4] = __builtin_amdgcn_mfma_f32_16x16x32_bf16(kf, qf[1], sc[s4], 0, 0, 0);
        }

        // softmax numerator -> packed bf16 -> swizzled Ps
        {
            const bool msk = (kt == s);
            #pragma unroll
            for (int s4 = 0; s4 < 4; ++s4) {
                float p[4];
                #pragma unroll
                for (int r = 0; r < 4; ++r) p[r] = fexp2(sc[s4][r]);
                if (msk) {   // diagonal tile only: uniform branch, per-lane mask
                    #pragma unroll
                    for (int r = 0; r < 4; ++r) {
                        const int key = k0 + s4 * 16 + quad * 4 + r;
                        if (key > q_) p[r] = 0.f;
                    }
                }
                uint2 pkv; pkv.x = pk2(p[0], p[1]); pkv.y = pk2(p[2], p[3]);
                const int col8 = (s4 * 4 + quad) ^ (e7 << 1);
                *(uint2*)&Ps[w][l15][col8 * 4] = pkv;
            }
        }

        // PV: O^T += V^T P^T  (+ row-sum via ones)
        #pragma unroll
        for (int kc = 0; kc < 2; ++kc) {
            const int c16 = ((kc * 4 + quad) ^ e7) * 8;
            const v8s pf = *(const v8s*)&Ps[w][l15][c16];
            os = __builtin_amdgcn_mfma_f32_16x16x32_bf16(ones, pf, os, 0, 0, 0);
            #pragma unroll
            for (int nf = 0; nf < 4; ++nf) {
                const v8s vf = *(const v8s*)&Vb[cur][nf * 16 + l15][c16];
                o[nf] = __builtin_amdgcn_mfma_f32_16x16x32_bf16(vf, pf, o[nf], 0, 0, 0);
            }
        }

        if (kt + 1 < nkt) {
            const int nxt = 1 - cur;
            *(v8s*)&Kb[nxt][srow][scolsw]      = kr0;
            *(v8s*)&Kb[nxt][srow + 32][scolsw] = kr1;
            *(v8s*)&Vb[nxt][srow][scolsw]      = vr0;
            *(v8s*)&Vb[nxt][srow + 32][scolsw] = vr1;
        }
        __syncthreads();
    }

    // every lane's os[0] holds the full row-sum for its query (all 4 regs equal)
    const float inv = 1.f / os[0];

    const int b = bh / HEADS, h = bh % HEADS;
    const size_t br = ((size_t)(b * 16 + (q0 >> 7)) * KT + h) * BRICK;
    const int rowl = (q0 & 127) + w * 16 + l15;
    #pragma unroll
    for (int nf = 0; nf < 4; ++nf) {
        uint2 a2;
        a2.x = pk2r(o[nf][0] * inv, o[nf][1] * inv);
        a2.y = pk2r(o[nf][2] * inv, o[nf][3] * inv);
        *(uint2*)(O + br + (size_t)rowl * 64 + nf * 16 + quad * 4) = a2;
    }
}

extern "C" void kernel_launch(void* const* d_in, const int* in_sizes, int n_in,
                              void* d_out, int out_size, void* d_ws, size_t ws_size,
                              hipStream_t stream) {
    const float* x  = (const float*)d_in[0];
    const float* Wq = (const float*)d_in[1];
    const float* bq = (const float*)d_in[2];
    const float* Wk = (const float*)d_in[3];
    const float* bk = (const float*)d_in[4];
    const float* Wv = (const float*)d_in[5];
    const float* bv = (const float*)d_in[6];
    const float* Wo = (const float*)d_in[7];
    const float* bo = (const float*)d_in[8];
    float* out = (float*)d_out;

    unsigned short* xb  = (unsigned short*)d_ws;      // tiled [8192][768] bf16; reused as ob
    unsigned short* qb  = xb  + NE;                   // [bh][s][64]
    unsigned short* kb  = qb  + NE;                   // [bh][s][64]
    unsigned short* vtb = kb  + NE;                   // [bh][64][s]
    unsigned short* wt  = vtb + NE;                   // 4 x [768][768] bf16 tiled (q,k,v,o)
    unsigned short* ob  = xb;                         // alias (xb dead after gemm_qkv)

    cvt_x_kernel<<<dim3(NE / (8 * 256)), 256, 0, stream>>>(x, xb);
    cvt_w_kernel<<<dim3(12, 12, 4), 256, 0, stream>>>(Wq, Wk, Wv, Wo, wt);
    gemm_qkv_kernel<<<dim3(1152), 256, 0, stream>>>(xb, wt, bq, bk, bv, qb, kb, vtb);
    attn_kernel<<<dim3(1536), 256, 0, stream>>>(qb, kb, vtb, ob);
    gemm_out_kernel<<<dim3(768), 256, 0, stream>>>(ob, wt + (size_t)3 * DM * DM, bo, out);
}